// Round 11
// baseline (185.201 us; speedup 1.0000x reference)
//
#include <hip/hip_runtime.h>

#define T_LEN 512
#define NHID 16
#define NEMB 10
#define VOCAB1 50001
#define IROW 521   // idx row len (ints): max ref t+11 = 519

typedef float v2f __attribute__((ext_vector_type(2)));

// ---------------------------------------------------------------------------
// Kernel 1: xproj table, layout [v][hi][j] float2 (R3-proven):
//   t2[v*32 + j]      = {i,f} pre-activations for unit j
//   t2[v*32 + 16 + j] = {g,o}
// ---------------------------------------------------------------------------
__global__ __launch_bounds__(256) void build_table2(
    const float* __restrict__ emb, const float* __restrict__ Wih,
    const float* __restrict__ bih, const float* __restrict__ bhh,
    float* __restrict__ tbl)
{
    const int tid = blockIdx.x * 256 + threadIdx.x;
    if (tid >= VOCAB1 * 16) return;
    const int v = tid >> 4, j = tid & 15;
    float e[NEMB];
    #pragma unroll
    for (int i = 0; i < NEMB; ++i) e[i] = emb[v * NEMB + i];
    float o[4];
    #pragma unroll
    for (int q = 0; q < 4; ++q) {
        const int r = q * 16 + j;
        float a = bih[r] + bhh[r];
        #pragma unroll
        for (int i = 0; i < NEMB; ++i) a += e[i] * Wih[r * NEMB + i];
        o[q] = a;
    }
    float2* t2 = (float2*)tbl;
    t2[v * 32 + j]      = make_float2(o[0], o[1]);   // i, f
    t2[v * 32 + 16 + j] = make_float2(o[2], o[3]);   // g, o
}

// ROW_ROR:r within 16-lane DPP row: D[l] = S[(l-r)&15]  (HW-verified R8/R10)
#define ROR_F(hvi, r) __builtin_bit_cast(float, \
    __builtin_amdgcn_update_dpp(0, hvi, 0x120 + (r), 0xF, 0xF, true))

// ---------------------------------------------------------------------------
// Kernel 2: GATE-SPLIT, 32 lanes/batch -> 2048 waves (2/SIMD).
// Lane (hi, j): computes gate pair {2hi, 2hi+1} for unit j:
//   hi=0 -> (i, f); hi=1 -> (g, o).  16 pk_fma + 2 nonlins per lane.
// Post-transcendental gate values exchanged via ds_swizzle xor16 (R9-proven);
// both halves duplicate the cheap c/h tail (bit-identical, R3-proven), so h
// lives in every lane and the next step's h-broadcast is R10's DPP row_ror
// with pair-packed permuted weights. 4-deep compile-time table pipeline +
// register idx prefetch (R10). LDS only for idx staging.
// ---------------------------------------------------------------------------
__global__ __launch_bounds__(256) void lstm_gs_kernel(
    const int*   __restrict__ x,
    const float* __restrict__ tbl,
    const float* __restrict__ Whh,
    const float* __restrict__ Wfc,
    const float* __restrict__ bfc,
    float*       __restrict__ out)
{
    __shared__ int idxs[8][IROW];    // [batch][t] token*32 (float2-row idx), 16.7 KB

    const int tid = threadIdx.x;
    const int l   = tid & 63;
    const int j   = l & 15;          // hidden unit owned
    const int hi  = (l >> 4) & 1;    // gate half: 0 -> i,f ; 1 -> g,o
    const int lb  = tid >> 5;        // local batch 0..7
    const int batch = blockIdx.x * 8 + lb;

    // stage tokens, pre-scaled to float2-row base (v*32); tail -> 0
    #pragma unroll 1
    for (int b = 0; b < 8; ++b) {
        const int* xr = x + (size_t)(blockIdx.x * 8 + b) * T_LEN;
        for (int t = tid; t < IROW; t += 256)
            idxs[b][t] = (t < T_LEN) ? (xr[t] << 5) : 0;
    }
    __syncthreads();

    // pair-packed permuted weights for this lane's 2 gate rows:
    //   rA = 2hi*16 + j (gate 2hi), rB = rA + 16 (gate 2hi+1)
    //   wpX[s] = { W[rX][(j-2s)&15], W[rX][(j-2s-1)&15] }  (matches DPP pairs)
    v2f wpA[8], wpB[8];
    {
        const int rA = (2 * hi) * 16 + j;
        const int rB = rA + 16;
        #pragma unroll
        for (int s = 0; s < 8; ++s) {
            const int k0 = (j - 2 * s) & 15, k1 = (j - 2 * s - 1) & 15;
            wpA[s] = (v2f){Whh[rA * NHID + k0], Whh[rA * NHID + k1]};
            wpB[s] = (v2f){Whh[rB * NHID + k0], Whh[rB * NHID + k1]};
        }
    }

    const float NL2E  = -1.44269504088896f;
    const float NL2E2 = -2.88539008177793f;
    const bool  hib = (hi != 0);
    const float sA = hib ? NL2E2 : NL2E;   // gate A: sigmoid (i) or tanh (g)
    const float mA = hib ? 2.f : 1.f;
    const float bA = hib ? -1.f : 0.f;

    float h = 0.f, c = 0.f;
    const float2* t2 = (const float2*)tbl;
    const int foff = hi * 16 + j;

    // 4-deep table pipeline + register idx prefetch (one macro-iter ahead)
    float2 pf[4];
    int iv[4];
    #pragma unroll
    for (int s = 0; s < 4; ++s) {
        pf[s] = t2[idxs[lb][s] + foff];
        iv[s] = idxs[lb][4 + s];
    }

    #pragma unroll 1
    for (int t = 0; t < T_LEN; t += 4) {
        int ivn[4];
        #pragma unroll
        for (int u = 0; u < 4; ++u) ivn[u] = idxs[lb][t + 8 + u];

        #pragma unroll
        for (int u = 0; u < 4; ++u) {
            const float2 tb = pf[u];
            pf[u] = t2[iv[u] + foff];        // in flight 4 steps (counted vmcnt)

            // h-broadcast within the 16-lane row (h identical in both rows)
            const int hvi = __builtin_bit_cast(int, h);
            v2f hrp[8];
            hrp[0] = (v2f){h,             ROR_F(hvi, 1)};
            hrp[1] = (v2f){ROR_F(hvi, 2),  ROR_F(hvi, 3)};
            hrp[2] = (v2f){ROR_F(hvi, 4),  ROR_F(hvi, 5)};
            hrp[3] = (v2f){ROR_F(hvi, 6),  ROR_F(hvi, 7)};
            hrp[4] = (v2f){ROR_F(hvi, 8),  ROR_F(hvi, 9)};
            hrp[5] = (v2f){ROR_F(hvi, 10), ROR_F(hvi, 11)};
            hrp[6] = (v2f){ROR_F(hvi, 12), ROR_F(hvi, 13)};
            hrp[7] = (v2f){ROR_F(hvi, 14), ROR_F(hvi, 15)};

            // two 16-wide gate dots, 2 accumulators each (pk_fma)
            v2f aA0 = (v2f){tb.x, 0.f}, aA1 = (v2f){0.f, 0.f};
            v2f aB0 = (v2f){tb.y, 0.f}, aB1 = (v2f){0.f, 0.f};
            #pragma unroll
            for (int s = 0; s < 4; ++s) {
                aA0 += hrp[s] * wpA[s];  aA1 += hrp[s + 4] * wpA[s + 4];
                aB0 += hrp[s] * wpB[s];  aB1 += hrp[s + 4] * wpB[s + 4];
            }
            const v2f sAv = aA0 + aA1, sBv = aB0 + aB1;
            const float vA = sAv.x + sAv.y;
            const float vB = sBv.x + sBv.y;

            // this lane's 2 nonlinearities (per-lane fused constants, R3)
            const float gA = __builtin_amdgcn_rcpf(1.f + __builtin_amdgcn_exp2f(vA * sA)) * mA + bA;
            const float gB = __builtin_amdgcn_rcpf(1.f + __builtin_amdgcn_exp2f(vB * NL2E));

            // exchange post-trans gates with the other half (lane ^ 16)
            const float othA = __builtin_bit_cast(float,
                __builtin_amdgcn_ds_swizzle(__builtin_bit_cast(int, gA), 0x401F));
            const float othB = __builtin_bit_cast(float,
                __builtin_amdgcn_ds_swizzle(__builtin_bit_cast(int, gB), 0x401F));

            const float ii = hib ? othA : gA;
            const float ff = hib ? othB : gB;
            const float gg = hib ? gA : othA;
            const float oo = hib ? gB : othB;

            // cheap duplicated tail -> bit-identical h in both halves
            c = ff * c + ii * gg;
            const float tc = 2.f * __builtin_amdgcn_rcpf(1.f + __builtin_amdgcn_exp2f(c * NL2E2)) - 1.f;
            h = oo * tc;
        }

        #pragma unroll
        for (int u = 0; u < 4; ++u) iv[u] = ivn[u];
    }

    // logit: reduce h*Wfc within each 16-lane row (epilogue only)
    float s = h * Wfc[j];
    s += __shfl_xor(s, 1, 64);
    s += __shfl_xor(s, 2, 64);
    s += __shfl_xor(s, 4, 64);
    s += __shfl_xor(s, 8, 64);
    if ((l & 31) == 0)
        out[batch] = __builtin_amdgcn_rcpf(1.f + __builtin_amdgcn_exp2f((s + bfc[0]) * NL2E));
}

// ---------------------------------------------------------------------------
// Fallback (ws too small for the 12.8 MB table): on-the-fly fp32 path.
// ---------------------------------------------------------------------------
__global__ __launch_bounds__(256) void lstm_fb_kernel(
    const int*   __restrict__ x,
    const float* __restrict__ emb,
    const float* __restrict__ Wih,
    const float* __restrict__ Whh,
    const float* __restrict__ bih,
    const float* __restrict__ bhh,
    const float* __restrict__ Wfc,
    const float* __restrict__ bfc,
    float*       __restrict__ out)
{
    __shared__ int   idx_lds[T_LEN][17];
    __shared__ float hx[16][20];

    const int tid  = threadIdx.x;
    const int lane = tid & 63;
    const int j    = lane & 15;
    const int lb   = tid >> 4;
    const int batch = blockIdx.x * 16 + lb;

    for (int i = tid; i < 16 * T_LEN; i += 256) {
        const int b = i & 15;
        const int t = i >> 4;
        idx_lds[t][b] = x[(blockIdx.x * 16 + b) * T_LEN + t];
    }

    float wih[4][NEMB], bias[4];
    v2f w[4][8];
    #pragma unroll
    for (int q = 0; q < 4; ++q) {
        const int r = j + 16 * q;
        #pragma unroll
        for (int e = 0; e < NEMB; ++e) wih[q][e] = Wih[r * NEMB + e];
        #pragma unroll
        for (int p = 0; p < 8; ++p)
            w[q][p] = (v2f){Whh[r * NHID + 2 * p], Whh[r * NHID + 2 * p + 1]};
        bias[q] = bih[r] + bhh[r];
    }

    __syncthreads();

    v2f h2[8];
    #pragma unroll
    for (int p = 0; p < 8; ++p) h2[p] = (v2f){0.f, 0.f};
    float c = 0.f;

    const float NL2E  = -1.44269504088896f;
    const float NL2E2 = -2.88539008177793f;
    const float4* hp = (const float4*)&hx[lb][0];

    float2 xa, xb, xc, xd, xe2;
    {
        const float2* er = (const float2*)(emb + (long)idx_lds[0][lb] * NEMB);
        xa = er[0]; xb = er[1]; xc = er[2]; xd = er[3]; xe2 = er[4];
    }
    int idx_n = idx_lds[1][lb];

    #pragma unroll 1
    for (int t = 0; t < T_LEN; ++t) {
        const float xv[NEMB] = {xa.x, xa.y, xb.x, xb.y, xc.x, xc.y,
                                xd.x, xd.y, xe2.x, xe2.y};
        if (t + 1 < T_LEN) {
            const float2* er = (const float2*)(emb + (long)idx_n * NEMB);
            xa = er[0]; xb = er[1]; xc = er[2]; xd = er[3]; xe2 = er[4];
        }
        const int idx_nn = (t + 2 < T_LEN) ? idx_lds[t + 2][lb] : 0;

        float v[4];
        #pragma unroll
        for (int q = 0; q < 4; ++q) {
            float a = bias[q];
            #pragma unroll
            for (int e = 0; e < NEMB; ++e) a += xv[e] * wih[q][e];
            v[q] = a;
        }
        v2f a0 = (v2f){v[0], 0.f}, a1 = (v2f){v[1], 0.f};
        v2f a2 = (v2f){v[2], 0.f}, a3 = (v2f){v[3], 0.f};
        #pragma unroll
        for (int p = 0; p < 8; ++p) {
            a0 += h2[p] * w[0][p];
            a1 += h2[p] * w[1][p];
            a2 += h2[p] * w[2][p];
            a3 += h2[p] * w[3][p];
        }
        const float vi = a0.x + a0.y, vf = a1.x + a1.y;
        const float vg = a2.x + a2.y, vo = a3.x + a3.y;

        const float ig = __builtin_amdgcn_rcpf(1.f + __builtin_amdgcn_exp2f(vi * NL2E));
        const float fg = __builtin_amdgcn_rcpf(1.f + __builtin_amdgcn_exp2f(vf * NL2E));
        const float gg = 2.f * __builtin_amdgcn_rcpf(1.f + __builtin_amdgcn_exp2f(vg * NL2E2)) - 1.f;
        const float og = __builtin_amdgcn_rcpf(1.f + __builtin_amdgcn_exp2f(vo * NL2E));

        c = fg * c + ig * gg;
        const float tc = 2.f * __builtin_amdgcn_rcpf(1.f + __builtin_amdgcn_exp2f(c * NL2E2)) - 1.f;
        const float hv = og * tc;

        hx[lb][j] = hv;
        const float4 b0 = hp[0], b1 = hp[1], b2 = hp[2], b3 = hp[3];
        h2[0] = (v2f){b0.x, b0.y}; h2[1] = (v2f){b0.z, b0.w};
        h2[2] = (v2f){b1.x, b1.y}; h2[3] = (v2f){b1.z, b1.w};
        h2[4] = (v2f){b2.x, b2.y}; h2[5] = (v2f){b2.z, b2.w};
        h2[6] = (v2f){b3.x, b3.y}; h2[7] = (v2f){b3.z, b3.w};

        idx_n = idx_nn;
    }

    if (j == 0) {
        float logit = bfc[0];
        #pragma unroll
        for (int p = 0; p < 8; ++p)
            logit += h2[p].x * Wfc[2 * p] + h2[p].y * Wfc[2 * p + 1];
        out[batch] = __builtin_amdgcn_rcpf(1.f + __builtin_amdgcn_exp2f(logit * NL2E));
    }
}

extern "C" void kernel_launch(void* const* d_in, const int* in_sizes, int n_in,
                              void* d_out, int out_size, void* d_ws, size_t ws_size,
                              hipStream_t stream) {
    const int*   x   = (const int*)  d_in[0];
    const float* emb = (const float*)d_in[1];
    const float* Wih = (const float*)d_in[2];
    const float* Whh = (const float*)d_in[3];
    const float* bih = (const float*)d_in[4];
    const float* bhh = (const float*)d_in[5];
    const float* Wfc = (const float*)d_in[6];
    const float* bfc = (const float*)d_in[7];
    float* outp = (float*)d_out;

    const int B = in_sizes[0] / T_LEN;                               // 4096
    const size_t TABLE_BYTES = (size_t)VOCAB1 * 64 * sizeof(float);  // 12.8 MB

    if (ws_size >= TABLE_BYTES) {
        float* tbl = (float*)d_ws;
        build_table2<<<(VOCAB1 * 16 + 255) / 256, 256, 0, stream>>>(emb, Wih, bih, bhh, tbl);
        lstm_gs_kernel<<<B / 8, 256, 0, stream>>>(x, tbl, Whh, Wfc, bfc, outp);
    } else {
        lstm_fb_kernel<<<B / 16, 256, 0, stream>>>(x, emb, Wih, Whh, bih, bhh, Wfc, bfc, outp);
    }
}